// Round 8
// baseline (414.759 us; speedup 1.0000x reference)
//
#include <hip/hip_runtime.h>

#define N_NODES   100000
#define N_PAD     100096           // 782 * 128
#define N_EDGES   1600000
#define IN_FEAT   64
#define HIDDEN    128
#define N_CLASSES 16
#define N_GRAPHS  512
#define MAXDEG    64               // Poisson(16): P(deg>=64) ~ e^-126, never

#define BIN_NODES 512              // nodes per bin (dst >> 9)
#define NBINS     196              // ceil(100000 / 512)
#define N_NODES_B (NBINS * BIN_NODES)   // 100352 (csr/cursor allocated size)
#define BINCAP    9000             // Poisson(8192) + ~9 sigma
#define EPB       2048             // edges per phase-1 block

typedef __attribute__((ext_vector_type(8))) unsigned short us8;   // 8 bf16
typedef __attribute__((ext_vector_type(8))) short s8v;            // mfma frag_ab
typedef __attribute__((ext_vector_type(4))) float f4v;            // mfma frag_cd

__device__ __forceinline__ unsigned short f2bf(float f) {
    unsigned u = __builtin_bit_cast(unsigned, f);
    unsigned r = u + 0x7FFFu + ((u >> 16) & 1u);    // RNE
    return (unsigned short)(r >> 16);
}
__device__ __forceinline__ float bf2f(unsigned short h) {
    unsigned u = ((unsigned)h) << 16;
    return __builtin_bit_cast(float, u);
}
__device__ __forceinline__ void acc8(float* a, us8 v) {
#pragma unroll
    for (int e = 0; e < 8; e++) a[e] += bf2f(v[e]);
}

// ---------------- CSR build phase 1: bin edges by dst>>9 ----------------

__global__ __launch_bounds__(512) void bin_kernel(const int* __restrict__ src,
                                                  const int* __restrict__ dst,
                                                  int* __restrict__ bin_cursor,
                                                  int2* __restrict__ binbuf) {
    __shared__ int hist[NBINS];
    __shared__ int base[NBINS];
    const int t = threadIdx.x;
    for (int i = t; i < NBINS; i += 512) hist[i] = 0;
    __syncthreads();

    const int e0 = blockIdx.x * EPB;
    int myb[4], mys[4], myd[4], myp[4];
#pragma unroll
    for (int j = 0; j < 4; j++) {
        int e = e0 + t + j * 512;
        if (e < N_EDGES) {
            myd[j] = dst[e];
            mys[j] = src[e];
            myb[j] = myd[j] >> 9;
        } else {
            myb[j] = -1; mys[j] = 0; myd[j] = 0;
        }
    }
#pragma unroll
    for (int j = 0; j < 4; j++)
        myp[j] = (myb[j] >= 0) ? atomicAdd(&hist[myb[j]], 1) : 0;
    __syncthreads();

    for (int i = t; i < NBINS; i += 512) {
        int h = hist[i];
        base[i] = (h > 0) ? atomicAdd(&bin_cursor[i], h) : 0;
    }
    __syncthreads();

#pragma unroll
    for (int j = 0; j < 4; j++) {
        if (myb[j] >= 0) {
            int pos = base[myb[j]] + myp[j];
            if (pos < BINCAP)
                binbuf[(size_t)myb[j] * BINCAP + pos] = make_int2(mys[j], myd[j]);
        }
    }
}

// ---------------- CSR build phase 2: per-bin scatter in LDS, coalesced writeout ------

__global__ __launch_bounds__(512) void build_kernel(const int2* __restrict__ binbuf,
                                                    const int* __restrict__ bin_cursor,
                                                    int* __restrict__ cursor,
                                                    int* __restrict__ csr) {
    __shared__ int lcur[BIN_NODES];                 // 2 KB
    __shared__ int lcsr[BIN_NODES * MAXDEG];        // 128 KB
    const int b = blockIdx.x, t = threadIdx.x;
    if (t < BIN_NODES) lcur[t] = 0;
    __syncthreads();

    int cnt = bin_cursor[b];
    if (cnt > BINCAP) cnt = BINCAP;
    const int2* __restrict__ eb = binbuf + (size_t)b * BINCAP;
    for (int i = t; i < cnt; i += 512) {
        int2 e = eb[i];
        int dl = e.y - b * BIN_NODES;               // 0..511
        int p = atomicAdd(&lcur[dl], 1);
        if (p < MAXDEG) lcsr[dl * MAXDEG + p] = e.x;
    }
    __syncthreads();

    // coalesced writeout: 32768 ints = 8192 int4
    int4* __restrict__ gout = reinterpret_cast<int4*>(csr + (size_t)b * BIN_NODES * MAXDEG);
    const int4* __restrict__ lin = reinterpret_cast<const int4*>(lcsr);
    for (int i = t; i < BIN_NODES * MAXDEG / 4; i += 512) gout[i] = lin[i];
    if (t < BIN_NODES) cursor[b * BIN_NODES + t] = lcur[t];
}

// ---------------- x -> bf16 (pad rows zeroed) ----------------

__global__ void convert_x_kernel(const float* __restrict__ x, ushort* __restrict__ xh) {
    const int flat = blockIdx.x * 256 + threadIdx.x;      // one us8 per thread
    const int row = flat >> 3;                             // 8 us8 per 64-feat row
    us8 w;
    if (row < N_NODES) {
        const float* p = x + (size_t)flat * 8;
        float4 v0 = *reinterpret_cast<const float4*>(p);
        float4 v1 = *reinterpret_cast<const float4*>(p + 4);
        w[0] = f2bf(v0.x); w[1] = f2bf(v0.y); w[2] = f2bf(v0.z); w[3] = f2bf(v0.w);
        w[4] = f2bf(v1.x); w[5] = f2bf(v1.y); w[6] = f2bf(v1.z); w[7] = f2bf(v1.w);
    } else {
#pragma unroll
        for (int e = 0; e < 8; e++) w[e] = 0;
    }
    reinterpret_cast<us8*>(xh)[flat] = w;
}

// ---------------- pack weights into MFMA fragment order (bf16) ----------------
// dst[((ks*8+ct)*64+lane)*8+j] = bf16( src[(ks*32+(lane>>4)*8+j)*128 + ct*16+(lane&15)] )

__global__ void pack_weights_kernel(const float* __restrict__ s0, const float* __restrict__ s1,
                                    const float* __restrict__ s2, const float* __restrict__ s3,
                                    const float* __restrict__ s4, const float* __restrict__ s5,
                                    ushort* __restrict__ Bpk) {
    const int flat = blockIdx.x * 256 + threadIdx.x;       // < 81920
    const float* src; int base;
    if      (flat < 8192)  { src = s0; base = 0; }
    else if (flat < 16384) { src = s1; base = 8192; }
    else if (flat < 32768) { src = s2; base = 16384; }
    else if (flat < 49152) { src = s3; base = 32768; }
    else if (flat < 65536) { src = s4; base = 49152; }
    else                   { src = s5; base = 65536; }
    const int local = flat - base;
    const int j    = local & 7;
    const int lane = (local >> 3) & 63;
    const int tile = local >> 9;
    const int ks = tile >> 3, ct = tile & 7;
    const int row = ks * 32 + ((lane >> 4) << 3) + j;
    const int col = (ct << 4) + (lane & 15);
    Bpk[flat] = f2bf(src[row * 128 + col]);
}

// ------- FUSED aggregate + GEMM: out = act( mean_nbr(feat)@B1 + feat@B2 + bias ) ------
// Each lane gathers and means EXACTLY its own MFMA A-fragments (2 rows x KS x 8 elems),
// then runs the barrier-free MFMA loop. B1p/B2p staged once in LDS (packed frag order).

template <int K, bool RELU>
__global__ __launch_bounds__(256, 2) void fused_agg_gemm(
        const ushort* __restrict__ feat,
        const int* __restrict__ cursor, const int* __restrict__ csr,
        const ushort* __restrict__ B1p, const ushort* __restrict__ B2p,
        const float* __restrict__ bias, ushort* __restrict__ out) {
    constexpr int KS = K / 32;
    __shared__ ushort Bs[2 * KS * 8 * 512];     // K=128: 64KB, K=64: 32KB
    const int tid = threadIdx.x;
    {   // stage both packed B matrices linearly into LDS
        const us8* g1 = reinterpret_cast<const us8*>(B1p);
        const us8* g2 = reinterpret_cast<const us8*>(B2p);
        us8* l8 = reinterpret_cast<us8*>(Bs);
        constexpr int PH = KS * 512;
#pragma unroll
        for (int i = 0; i < 4 * KS; i++) {
            int c = i * 256 + tid;
            if (i < 2 * KS) l8[c] = g1[c];
            else            l8[c] = g2[c - PH];
        }
    }
    __syncthreads();

    const int wave = tid >> 6, lane = tid & 63;
    const int r0 = blockIdx.x * 128 + wave * 32;
    const int rowbase = r0 + (lane & 15);
    const int koff = (lane >> 4) << 3;

    // ---- phase A: per-lane gather-mean of own A1 fragments ----
    s8v a1[2][KS];
#pragma unroll
    for (int rt = 0; rt < 2; rt++) {
        const int arow = rowbase + rt * 16;
        const int base = arow * MAXDEG;
        int cnt = cursor[arow];
        if (cnt > MAXDEG) cnt = MAXDEG;
        float accf[KS][8];
#pragma unroll
        for (int ks = 0; ks < KS; ks++)
#pragma unroll
            for (int j = 0; j < 8; j++) accf[ks][j] = 0.f;

        int i = 0;
        for (; i + 2 <= cnt; i += 2) {
            int s0 = csr[base + i], s1 = csr[base + i + 1];
            us8 v0[KS], v1[KS];
#pragma unroll
            for (int ks = 0; ks < KS; ks++) {
                v0[ks] = *reinterpret_cast<const us8*>(feat + (size_t)s0 * K + ks * 32 + koff);
                v1[ks] = *reinterpret_cast<const us8*>(feat + (size_t)s1 * K + ks * 32 + koff);
            }
#pragma unroll
            for (int ks = 0; ks < KS; ks++)
#pragma unroll
                for (int j = 0; j < 8; j++)
                    accf[ks][j] += bf2f(v0[ks][j]) + bf2f(v1[ks][j]);
        }
        if (i < cnt) {
            int s0 = csr[base + i];
#pragma unroll
            for (int ks = 0; ks < KS; ks++) {
                us8 v0 = *reinterpret_cast<const us8*>(feat + (size_t)s0 * K + ks * 32 + koff);
#pragma unroll
                for (int j = 0; j < 8; j++) accf[ks][j] += bf2f(v0[j]);
            }
        }
        const float inv = 1.f / (float)(cnt > 0 ? cnt : 1);
#pragma unroll
        for (int ks = 0; ks < KS; ks++) {
            s8v t;
#pragma unroll
            for (int j = 0; j < 8; j++) t[j] = (short)f2bf(accf[ks][j] * inv);
            a1[rt][ks] = t;
        }
    }

    // ---- phase B: MFMA ----
    f4v acc[2][8];
#pragma unroll
    for (int rt = 0; rt < 2; rt++)
#pragma unroll
        for (int ct = 0; ct < 8; ct++) acc[rt][ct] = (f4v){0.f, 0.f, 0.f, 0.f};

    const s8v* Bf = reinterpret_cast<const s8v*>(Bs);
#pragma unroll
    for (int ks = 0; ks < KS; ks++) {
#pragma unroll
        for (int ct = 0; ct < 8; ct++) {
            s8v b = Bf[(ks * 8 + ct) * 64 + lane];
            acc[0][ct] = __builtin_amdgcn_mfma_f32_16x16x32_bf16(a1[0][ks], b, acc[0][ct], 0, 0, 0);
            acc[1][ct] = __builtin_amdgcn_mfma_f32_16x16x32_bf16(a1[1][ks], b, acc[1][ct], 0, 0, 0);
        }
    }
#pragma unroll
    for (int ks = 0; ks < KS; ks++) {
        s8v s0 = *reinterpret_cast<const s8v*>(feat + (size_t)rowbase * K + ks * 32 + koff);
        s8v s1 = *reinterpret_cast<const s8v*>(feat + (size_t)(rowbase + 16) * K + ks * 32 + koff);
#pragma unroll
        for (int ct = 0; ct < 8; ct++) {
            s8v b = Bf[((KS + ks) * 8 + ct) * 64 + lane];
            acc[0][ct] = __builtin_amdgcn_mfma_f32_16x16x32_bf16(s0, b, acc[0][ct], 0, 0, 0);
            acc[1][ct] = __builtin_amdgcn_mfma_f32_16x16x32_bf16(s1, b, acc[1][ct], 0, 0, 0);
        }
    }

    // epilogue: C/D layout col=lane&15, row=(lane>>4)*4+reg  [m89]
    const int colb = lane & 15;
    const int rowb = (lane >> 4) << 2;
#pragma unroll
    for (int rt = 0; rt < 2; rt++) {
#pragma unroll
        for (int ct = 0; ct < 8; ct++) {
            const int col = ct * 16 + colb;
            const float bb = bias[col];
#pragma unroll
            for (int j = 0; j < 4; j++) {
                int row = r0 + rt * 16 + rowb + j;
                if (row < N_NODES) {
                    float v = acc[rt][ct][j] + bb;
                    if (RELU) v = fmaxf(v, 0.f);
                    out[(size_t)row * HIDDEN + col] = f2bf(v);
                }
            }
        }
    }
}

// ---------------- global mean pool (bf16 in, f32 out; one wave per graph) -------------

__global__ __launch_bounds__(256) void pool_bf(const ushort* __restrict__ h,
                                               const int* __restrict__ batch,
                                               float* __restrict__ g) {
    __shared__ int sb[5];
    const int g0 = blockIdx.x * 4;
    const int tid = threadIdx.x;
    if (tid <= 4) {
        int target = g0 + tid;
        int lo = 0, hi = N_NODES;
        while (lo < hi) {
            int mid = (lo + hi) >> 1;
            if (batch[mid] < target) lo = mid + 1; else hi = mid;
        }
        sb[tid] = lo;
    }
    __syncthreads();
    const int lg = tid >> 6;
    const int lane = tid & 63;
    const int s = sb[lg], e = sb[lg + 1];
    const int nsub = lane >> 4;
    const int cc = lane & 15;
    const us8* __restrict__ h8 = reinterpret_cast<const us8*>(h);

    float a[8] = {0.f, 0.f, 0.f, 0.f, 0.f, 0.f, 0.f, 0.f};
    int n = s + nsub;
    for (; n + 12 < e; n += 16) {
        us8 v0 = h8[(size_t)(n + 0) * 16 + cc];
        us8 v1 = h8[(size_t)(n + 4) * 16 + cc];
        us8 v2 = h8[(size_t)(n + 8) * 16 + cc];
        us8 v3 = h8[(size_t)(n + 12) * 16 + cc];
        acc8(a, v0); acc8(a, v1); acc8(a, v2); acc8(a, v3);
    }
    for (; n < e; n += 4) {
        us8 v0 = h8[(size_t)n * 16 + cc];
        acc8(a, v0);
    }
#pragma unroll
    for (int e2 = 0; e2 < 8; e2++) {
        a[e2] += __shfl_xor(a[e2], 16);
        a[e2] += __shfl_xor(a[e2], 32);
    }
    if (nsub == 0) {
        const int cnt = e - s;
        const float inv = 1.f / (float)(cnt > 0 ? cnt : 1);
        float4 w0 = make_float4(a[0] * inv, a[1] * inv, a[2] * inv, a[3] * inv);
        float4 w1 = make_float4(a[4] * inv, a[5] * inv, a[6] * inv, a[7] * inv);
        float* dst = g + (size_t)(g0 + lg) * HIDDEN + cc * 8;
        *reinterpret_cast<float4*>(dst) = w0;
        *reinterpret_cast<float4*>(dst + 4) = w1;
    }
}

// ---------------- output head: out = g @ W_out + b_out (f32 exact) ----------------

__global__ void head_kernel(const float* __restrict__ g, const float* __restrict__ W,
                            const float* __restrict__ b, float* __restrict__ out) {
    const int gid = blockIdx.x * 4 + (threadIdx.x >> 4);
    const int f = threadIdx.x & 15;
    if (gid >= N_GRAPHS) return;
    float acc = b[f];
    for (int k = 0; k < HIDDEN; k++)
        acc += g[(size_t)gid * HIDDEN + k] * W[k * N_CLASSES + f];
    out[(size_t)gid * N_CLASSES + f] = acc;
}

// ---------------- launch ----------------

extern "C" void kernel_launch(void* const* d_in, const int* in_sizes, int n_in,
                              void* d_out, int out_size, void* d_ws, size_t ws_size,
                              hipStream_t stream) {
    const float* x    = (const float*)d_in[0];
    const int* eidx   = (const int*)d_in[1];
    const int* batch  = (const int*)d_in[2];
    const float* Wl1  = (const float*)d_in[3];
    const float* bl1  = (const float*)d_in[4];
    const float* Wr1  = (const float*)d_in[5];
    const float* Wl2  = (const float*)d_in[6];
    const float* bl2  = (const float*)d_in[7];
    const float* Wr2  = (const float*)d_in[8];
    const float* Wl3  = (const float*)d_in[9];
    const float* bl3  = (const float*)d_in[10];
    const float* Wr3  = (const float*)d_in[11];
    const float* Wout = (const float*)d_in[12];
    const float* bout = (const float*)d_in[13];
    float* out = (float*)d_out;

    const int* esrc = eidx;
    const int* edst = eidx + N_EDGES;

    char* ws = (char*)d_ws;
    size_t o = 0;
    int*  bin_cursor = (int*)(ws + o);  o += 256 * 4;                        // zeroed
    int*  cursor     = (int*)(ws + o);  o += (size_t)N_NODES_B * 4;
    int*  csr        = (int*)(ws + o);  o += (size_t)N_NODES_B * MAXDEG * 4; // 25.7 MB
    int2* binbuf     = (int2*)(ws + o); o += (size_t)NBINS * BINCAP * 8;     // 14.1 MB
    o = (o + 255) & ~(size_t)255;
    ushort* xh   = (ushort*)(ws + o); o += (size_t)N_PAD * IN_FEAT * 2;
    ushort* h1b  = (ushort*)(ws + o); o += (size_t)N_PAD * HIDDEN * 2;
    ushort* h2b  = (ushort*)(ws + o); o += (size_t)N_PAD * HIDDEN * 2;
    ushort* Bpk  = (ushort*)(ws + o); o += (size_t)81920 * 2;
    float*  g    = (float*)(ws + o);  o += (size_t)N_GRAPHS * HIDDEN * 4;

    hipMemsetAsync(bin_cursor, 0, 256 * 4, stream);

    bin_kernel<<<(N_EDGES + EPB - 1) / EPB, 512, 0, stream>>>(esrc, edst, bin_cursor, binbuf);
    build_kernel<<<NBINS, 512, 0, stream>>>(binbuf, bin_cursor, cursor, csr);

    pack_weights_kernel<<<320, 256, 0, stream>>>(Wl1, Wr1, Wl2, Wr2, Wl3, Wr3, Bpk);
    convert_x_kernel<<<(N_PAD * IN_FEAT / 8) / 256, 256, 0, stream>>>(x, xh);

    ushort* Wl1p = Bpk + 0,     *Wr1p = Bpk + 8192;
    ushort* Wl2p = Bpk + 16384, *Wr2p = Bpk + 32768;
    ushort* Wl3p = Bpk + 49152, *Wr3p = Bpk + 65536;

    const int GB = N_PAD / 128;                       // 782

    // layer 1: fused aggregate(x) + [agg@Wl1 + x@Wr1] + relu
    fused_agg_gemm<IN_FEAT, true><<<GB, 256, 0, stream>>>(xh, cursor, csr, Wl1p, Wr1p, bl1, h1b);
    // layer 2
    fused_agg_gemm<HIDDEN, true><<<GB, 256, 0, stream>>>(h1b, cursor, csr, Wl2p, Wr2p, bl2, h2b);
    // layer 3 (no relu) -> write into h1b (free)
    fused_agg_gemm<HIDDEN, false><<<GB, 256, 0, stream>>>(h2b, cursor, csr, Wl3p, Wr3p, bl3, h1b);

    // pool + head
    pool_bf<<<N_GRAPHS / 4, 256, 0, stream>>>(h1b, batch, g);
    head_kernel<<<N_GRAPHS / 4, 64, 0, stream>>>(g, Wout, bout, out);
}

// Round 9
// 414.650 us; speedup vs baseline: 1.0003x; 1.0003x over previous
//
#include <hip/hip_runtime.h>

#define N_NODES   100000
#define N_PAD     100096           // 782 * 128
#define N_EDGES   1600000
#define IN_FEAT   64
#define HIDDEN    128
#define N_CLASSES 16
#define N_GRAPHS  512
#define MAXDEG    64               // Poisson(16): P(deg>=64) ~ e^-126, never

#define BIN_NODES 512              // nodes per bin (dst >> 9)
#define NBINS     196              // ceil(100000 / 512)
#define N_NODES_B (NBINS * BIN_NODES)   // 100352 (csr/cursor allocated size)
#define BINCAP    9000             // Poisson(8192) + ~9 sigma
#define EPB       2048             // edges per phase-1 block

typedef __attribute__((ext_vector_type(8))) unsigned short us8;   // 8 bf16
typedef __attribute__((ext_vector_type(8))) short s8v;            // mfma frag_ab
typedef __attribute__((ext_vector_type(4))) float f4v;            // mfma frag_cd

__device__ __forceinline__ unsigned short f2bf(float f) {
    unsigned u = __builtin_bit_cast(unsigned, f);
    unsigned r = u + 0x7FFFu + ((u >> 16) & 1u);    // RNE
    return (unsigned short)(r >> 16);
}
__device__ __forceinline__ float bf2f(unsigned short h) {
    unsigned u = ((unsigned)h) << 16;
    return __builtin_bit_cast(float, u);
}
__device__ __forceinline__ void acc8(float* a, us8 v) {
#pragma unroll
    for (int e = 0; e < 8; e++) a[e] += bf2f(v[e]);
}

// ---------------- CSR build phase 1: bin edges by dst>>9 ----------------

__global__ __launch_bounds__(512) void bin_kernel(const int* __restrict__ src,
                                                  const int* __restrict__ dst,
                                                  int* __restrict__ bin_cursor,
                                                  int2* __restrict__ binbuf) {
    __shared__ int hist[NBINS];
    __shared__ int base[NBINS];
    const int t = threadIdx.x;
    for (int i = t; i < NBINS; i += 512) hist[i] = 0;
    __syncthreads();

    const int e0 = blockIdx.x * EPB;
    int myb[4], mys[4], myd[4], myp[4];
#pragma unroll
    for (int j = 0; j < 4; j++) {
        int e = e0 + t + j * 512;
        if (e < N_EDGES) {
            myd[j] = dst[e];
            mys[j] = src[e];
            myb[j] = myd[j] >> 9;
        } else {
            myb[j] = -1; mys[j] = 0; myd[j] = 0;
        }
    }
#pragma unroll
    for (int j = 0; j < 4; j++)
        myp[j] = (myb[j] >= 0) ? atomicAdd(&hist[myb[j]], 1) : 0;
    __syncthreads();

    for (int i = t; i < NBINS; i += 512) {
        int h = hist[i];
        base[i] = (h > 0) ? atomicAdd(&bin_cursor[i], h) : 0;
    }
    __syncthreads();

#pragma unroll
    for (int j = 0; j < 4; j++) {
        if (myb[j] >= 0) {
            int pos = base[myb[j]] + myp[j];
            if (pos < BINCAP)
                binbuf[(size_t)myb[j] * BINCAP + pos] = make_int2(mys[j], myd[j]);
        }
    }
}

// ---------------- CSR build phase 2: per-bin scatter in LDS, coalesced writeout ------

__global__ __launch_bounds__(512) void build_kernel(const int2* __restrict__ binbuf,
                                                    const int* __restrict__ bin_cursor,
                                                    int* __restrict__ cursor,
                                                    int* __restrict__ csr) {
    __shared__ int lcur[BIN_NODES];                 // 2 KB
    __shared__ int lcsr[BIN_NODES * MAXDEG];        // 128 KB
    const int b = blockIdx.x, t = threadIdx.x;
    if (t < BIN_NODES) lcur[t] = 0;
    __syncthreads();

    int cnt = bin_cursor[b];
    if (cnt > BINCAP) cnt = BINCAP;
    const int2* __restrict__ eb = binbuf + (size_t)b * BINCAP;
    for (int i = t; i < cnt; i += 512) {
        int2 e = eb[i];
        int dl = e.y - b * BIN_NODES;               // 0..511
        int p = atomicAdd(&lcur[dl], 1);
        if (p < MAXDEG) lcsr[dl * MAXDEG + p] = e.x;
    }
    __syncthreads();

    // coalesced writeout: 32768 ints = 8192 int4
    int4* __restrict__ gout = reinterpret_cast<int4*>(csr + (size_t)b * BIN_NODES * MAXDEG);
    const int4* __restrict__ lin = reinterpret_cast<const int4*>(lcsr);
    for (int i = t; i < BIN_NODES * MAXDEG / 4; i += 512) gout[i] = lin[i];
    if (t < BIN_NODES) cursor[b * BIN_NODES + t] = lcur[t];
}

// ---------------- x -> bf16 (pad rows zeroed) ----------------

__global__ void convert_x_kernel(const float* __restrict__ x, ushort* __restrict__ xh) {
    const int flat = blockIdx.x * 256 + threadIdx.x;      // one us8 per thread
    const int row = flat >> 3;                             // 8 us8 per 64-feat row
    us8 w;
    if (row < N_NODES) {
        const float* p = x + (size_t)flat * 8;
        float4 v0 = *reinterpret_cast<const float4*>(p);
        float4 v1 = *reinterpret_cast<const float4*>(p + 4);
        w[0] = f2bf(v0.x); w[1] = f2bf(v0.y); w[2] = f2bf(v0.z); w[3] = f2bf(v0.w);
        w[4] = f2bf(v1.x); w[5] = f2bf(v1.y); w[6] = f2bf(v1.z); w[7] = f2bf(v1.w);
    } else {
#pragma unroll
        for (int e = 0; e < 8; e++) w[e] = 0;
    }
    reinterpret_cast<us8*>(xh)[flat] = w;
}

// ---------------- pack weights into MFMA fragment order (bf16) ----------------
// dst[((ks*8+ct)*64+lane)*8+j] = bf16( src[(ks*32+(lane>>4)*8+j)*128 + ct*16+(lane&15)] )

__global__ void pack_weights_kernel(const float* __restrict__ s0, const float* __restrict__ s1,
                                    const float* __restrict__ s2, const float* __restrict__ s3,
                                    const float* __restrict__ s4, const float* __restrict__ s5,
                                    ushort* __restrict__ Bpk) {
    const int flat = blockIdx.x * 256 + threadIdx.x;       // < 81920
    const float* src; int base;
    if      (flat < 8192)  { src = s0; base = 0; }
    else if (flat < 16384) { src = s1; base = 8192; }
    else if (flat < 32768) { src = s2; base = 16384; }
    else if (flat < 49152) { src = s3; base = 32768; }
    else if (flat < 65536) { src = s4; base = 49152; }
    else                   { src = s5; base = 65536; }
    const int local = flat - base;
    const int j    = local & 7;
    const int lane = (local >> 3) & 63;
    const int tile = local >> 9;
    const int ks = tile >> 3, ct = tile & 7;
    const int row = ks * 32 + ((lane >> 4) << 3) + j;
    const int col = (ct << 4) + (lane & 15);
    Bpk[flat] = f2bf(src[row * 128 + col]);
}

// ------- FUSED aggregate + GEMM: out = act( mean_nbr(feat)@B1 + feat@B2 + bias ) ------
// Each lane gathers and means EXACTLY its own MFMA A-fragments (2 rows x KS x 8 elems),
// then runs the MFMA loop. B fragments read DIRECTLY from global (160KB total, L1/L2
// resident across all 782 blocks) -- no LDS, no barrier, occupancy = VGPR-limited.

template <int K, bool RELU>
__global__ __launch_bounds__(256, 4) void fused_agg_gemm(
        const ushort* __restrict__ feat,
        const int* __restrict__ cursor, const int* __restrict__ csr,
        const ushort* __restrict__ B1p, const ushort* __restrict__ B2p,
        const float* __restrict__ bias, ushort* __restrict__ out) {
    constexpr int KS = K / 32;
    const int tid = threadIdx.x;
    const int wave = tid >> 6, lane = tid & 63;
    const int r0 = blockIdx.x * 128 + wave * 32;
    const int rowbase = r0 + (lane & 15);
    const int koff = (lane >> 4) << 3;

    // ---- phase A: per-lane gather-mean of own A1 fragments ----
    s8v a1[2][KS];
#pragma unroll
    for (int rt = 0; rt < 2; rt++) {
        const int arow = rowbase + rt * 16;
        const int base = arow * MAXDEG;
        int cnt = cursor[arow];
        if (cnt > MAXDEG) cnt = MAXDEG;
        float accf[KS][8];
#pragma unroll
        for (int ks = 0; ks < KS; ks++)
#pragma unroll
            for (int j = 0; j < 8; j++) accf[ks][j] = 0.f;

        int i = 0;
        for (; i + 2 <= cnt; i += 2) {
            int s0 = csr[base + i], s1 = csr[base + i + 1];
            us8 v0[KS], v1[KS];
#pragma unroll
            for (int ks = 0; ks < KS; ks++) {
                v0[ks] = *reinterpret_cast<const us8*>(feat + (size_t)s0 * K + ks * 32 + koff);
                v1[ks] = *reinterpret_cast<const us8*>(feat + (size_t)s1 * K + ks * 32 + koff);
            }
#pragma unroll
            for (int ks = 0; ks < KS; ks++)
#pragma unroll
                for (int j = 0; j < 8; j++)
                    accf[ks][j] += bf2f(v0[ks][j]) + bf2f(v1[ks][j]);
        }
        if (i < cnt) {
            int s0 = csr[base + i];
#pragma unroll
            for (int ks = 0; ks < KS; ks++) {
                us8 v0 = *reinterpret_cast<const us8*>(feat + (size_t)s0 * K + ks * 32 + koff);
#pragma unroll
                for (int j = 0; j < 8; j++) accf[ks][j] += bf2f(v0[j]);
            }
        }
        const float inv = 1.f / (float)(cnt > 0 ? cnt : 1);
#pragma unroll
        for (int ks = 0; ks < KS; ks++) {
            s8v t;
#pragma unroll
            for (int j = 0; j < 8; j++) t[j] = (short)f2bf(accf[ks][j] * inv);
            a1[rt][ks] = t;
        }
    }

    // ---- phase B: MFMA (B frags from global; same addresses for every wave -> L1 hits)
    f4v acc[2][8];
#pragma unroll
    for (int rt = 0; rt < 2; rt++)
#pragma unroll
        for (int ct = 0; ct < 8; ct++) acc[rt][ct] = (f4v){0.f, 0.f, 0.f, 0.f};

    const s8v* __restrict__ Bf1 = reinterpret_cast<const s8v*>(B1p);
    const s8v* __restrict__ Bf2 = reinterpret_cast<const s8v*>(B2p);
#pragma unroll
    for (int ks = 0; ks < KS; ks++) {
#pragma unroll
        for (int ct = 0; ct < 8; ct++) {
            s8v b = Bf1[(ks * 8 + ct) * 64 + lane];
            acc[0][ct] = __builtin_amdgcn_mfma_f32_16x16x32_bf16(a1[0][ks], b, acc[0][ct], 0, 0, 0);
            acc[1][ct] = __builtin_amdgcn_mfma_f32_16x16x32_bf16(a1[1][ks], b, acc[1][ct], 0, 0, 0);
        }
    }
#pragma unroll
    for (int ks = 0; ks < KS; ks++) {
        s8v s0 = *reinterpret_cast<const s8v*>(feat + (size_t)rowbase * K + ks * 32 + koff);
        s8v s1 = *reinterpret_cast<const s8v*>(feat + (size_t)(rowbase + 16) * K + ks * 32 + koff);
#pragma unroll
        for (int ct = 0; ct < 8; ct++) {
            s8v b = Bf2[(ks * 8 + ct) * 64 + lane];
            acc[0][ct] = __builtin_amdgcn_mfma_f32_16x16x32_bf16(s0, b, acc[0][ct], 0, 0, 0);
            acc[1][ct] = __builtin_amdgcn_mfma_f32_16x16x32_bf16(s1, b, acc[1][ct], 0, 0, 0);
        }
    }

    // epilogue: C/D layout col=lane&15, row=(lane>>4)*4+reg  [m89]
    const int colb = lane & 15;
    const int rowb = (lane >> 4) << 2;
#pragma unroll
    for (int rt = 0; rt < 2; rt++) {
#pragma unroll
        for (int ct = 0; ct < 8; ct++) {
            const int col = ct * 16 + colb;
            const float bb = bias[col];
#pragma unroll
            for (int j = 0; j < 4; j++) {
                int row = r0 + rt * 16 + rowb + j;
                if (row < N_NODES) {
                    float v = acc[rt][ct][j] + bb;
                    if (RELU) v = fmaxf(v, 0.f);
                    out[(size_t)row * HIDDEN + col] = f2bf(v);
                }
            }
        }
    }
}

// ---------------- global mean pool (bf16 in, f32 out; one wave per graph) -------------

__global__ __launch_bounds__(256) void pool_bf(const ushort* __restrict__ h,
                                               const int* __restrict__ batch,
                                               float* __restrict__ g) {
    __shared__ int sb[5];
    const int g0 = blockIdx.x * 4;
    const int tid = threadIdx.x;
    if (tid <= 4) {
        int target = g0 + tid;
        int lo = 0, hi = N_NODES;
        while (lo < hi) {
            int mid = (lo + hi) >> 1;
            if (batch[mid] < target) lo = mid + 1; else hi = mid;
        }
        sb[tid] = lo;
    }
    __syncthreads();
    const int lg = tid >> 6;
    const int lane = tid & 63;
    const int s = sb[lg], e = sb[lg + 1];
    const int nsub = lane >> 4;
    const int cc = lane & 15;
    const us8* __restrict__ h8 = reinterpret_cast<const us8*>(h);

    float a[8] = {0.f, 0.f, 0.f, 0.f, 0.f, 0.f, 0.f, 0.f};
    int n = s + nsub;
    for (; n + 12 < e; n += 16) {
        us8 v0 = h8[(size_t)(n + 0) * 16 + cc];
        us8 v1 = h8[(size_t)(n + 4) * 16 + cc];
        us8 v2 = h8[(size_t)(n + 8) * 16 + cc];
        us8 v3 = h8[(size_t)(n + 12) * 16 + cc];
        acc8(a, v0); acc8(a, v1); acc8(a, v2); acc8(a, v3);
    }
    for (; n < e; n += 4) {
        us8 v0 = h8[(size_t)n * 16 + cc];
        acc8(a, v0);
    }
#pragma unroll
    for (int e2 = 0; e2 < 8; e2++) {
        a[e2] += __shfl_xor(a[e2], 16);
        a[e2] += __shfl_xor(a[e2], 32);
    }
    if (nsub == 0) {
        const int cnt = e - s;
        const float inv = 1.f / (float)(cnt > 0 ? cnt : 1);
        float4 w0 = make_float4(a[0] * inv, a[1] * inv, a[2] * inv, a[3] * inv);
        float4 w1 = make_float4(a[4] * inv, a[5] * inv, a[6] * inv, a[7] * inv);
        float* dst = g + (size_t)(g0 + lg) * HIDDEN + cc * 8;
        *reinterpret_cast<float4*>(dst) = w0;
        *reinterpret_cast<float4*>(dst + 4) = w1;
    }
}

// ---------------- output head: out = g @ W_out + b_out (f32 exact) ----------------

__global__ void head_kernel(const float* __restrict__ g, const float* __restrict__ W,
                            const float* __restrict__ b, float* __restrict__ out) {
    const int gid = blockIdx.x * 4 + (threadIdx.x >> 4);
    const int f = threadIdx.x & 15;
    if (gid >= N_GRAPHS) return;
    float acc = b[f];
    for (int k = 0; k < HIDDEN; k++)
        acc += g[(size_t)gid * HIDDEN + k] * W[k * N_CLASSES + f];
    out[(size_t)gid * N_CLASSES + f] = acc;
}

// ---------------- launch ----------------

extern "C" void kernel_launch(void* const* d_in, const int* in_sizes, int n_in,
                              void* d_out, int out_size, void* d_ws, size_t ws_size,
                              hipStream_t stream) {
    const float* x    = (const float*)d_in[0];
    const int* eidx   = (const int*)d_in[1];
    const int* batch  = (const int*)d_in[2];
    const float* Wl1  = (const float*)d_in[3];
    const float* bl1  = (const float*)d_in[4];
    const float* Wr1  = (const float*)d_in[5];
    const float* Wl2  = (const float*)d_in[6];
    const float* bl2  = (const float*)d_in[7];
    const float* Wr2  = (const float*)d_in[8];
    const float* Wl3  = (const float*)d_in[9];
    const float* bl3  = (const float*)d_in[10];
    const float* Wr3  = (const float*)d_in[11];
    const float* Wout = (const float*)d_in[12];
    const float* bout = (const float*)d_in[13];
    float* out = (float*)d_out;

    const int* esrc = eidx;
    const int* edst = eidx + N_EDGES;

    char* ws = (char*)d_ws;
    size_t o = 0;
    int*  bin_cursor = (int*)(ws + o);  o += 256 * 4;                        // zeroed
    int*  cursor     = (int*)(ws + o);  o += (size_t)N_NODES_B * 4;
    int*  csr        = (int*)(ws + o);  o += (size_t)N_NODES_B * MAXDEG * 4; // 25.7 MB
    int2* binbuf     = (int2*)(ws + o); o += (size_t)NBINS * BINCAP * 8;     // 14.1 MB
    o = (o + 255) & ~(size_t)255;
    ushort* xh   = (ushort*)(ws + o); o += (size_t)N_PAD * IN_FEAT * 2;
    ushort* h1b  = (ushort*)(ws + o); o += (size_t)N_PAD * HIDDEN * 2;
    ushort* h2b  = (ushort*)(ws + o); o += (size_t)N_PAD * HIDDEN * 2;
    ushort* Bpk  = (ushort*)(ws + o); o += (size_t)81920 * 2;
    float*  g    = (float*)(ws + o);  o += (size_t)N_GRAPHS * HIDDEN * 4;

    hipMemsetAsync(bin_cursor, 0, 256 * 4, stream);

    bin_kernel<<<(N_EDGES + EPB - 1) / EPB, 512, 0, stream>>>(esrc, edst, bin_cursor, binbuf);
    build_kernel<<<NBINS, 512, 0, stream>>>(binbuf, bin_cursor, cursor, csr);

    pack_weights_kernel<<<320, 256, 0, stream>>>(Wl1, Wr1, Wl2, Wr2, Wl3, Wr3, Bpk);
    convert_x_kernel<<<(N_PAD * IN_FEAT / 8) / 256, 256, 0, stream>>>(x, xh);

    ushort* Wl1p = Bpk + 0,     *Wr1p = Bpk + 8192;
    ushort* Wl2p = Bpk + 16384, *Wr2p = Bpk + 32768;
    ushort* Wl3p = Bpk + 49152, *Wr3p = Bpk + 65536;

    const int GB = N_PAD / 128;                       // 782

    // layer 1: fused aggregate(x) + [agg@Wl1 + x@Wr1] + relu
    fused_agg_gemm<IN_FEAT, true><<<GB, 256, 0, stream>>>(xh, cursor, csr, Wl1p, Wr1p, bl1, h1b);
    // layer 2
    fused_agg_gemm<HIDDEN, true><<<GB, 256, 0, stream>>>(h1b, cursor, csr, Wl2p, Wr2p, bl2, h2b);
    // layer 3 (no relu) -> write into h1b (free)
    fused_agg_gemm<HIDDEN, false><<<GB, 256, 0, stream>>>(h2b, cursor, csr, Wl3p, Wr3p, bl3, h1b);

    // pool + head
    pool_bf<<<N_GRAPHS / 4, 256, 0, stream>>>(h1b, batch, g);
    head_kernel<<<N_GRAPHS / 4, 64, 0, stream>>>(g, Wout, bout, out);
}

// Round 10
// 372.779 us; speedup vs baseline: 1.1126x; 1.1123x over previous
//
#include <hip/hip_runtime.h>

#define N_NODES   100000
#define N_PAD     100096           // 782 * 128
#define N_EDGES   1600000
#define IN_FEAT   64
#define HIDDEN    128
#define N_CLASSES 16
#define N_GRAPHS  512
#define MAXDEG    64               // Poisson(16): P(deg>=64) ~ e^-126, never

#define BIN_NODES 512              // nodes per bin (dst >> 9)
#define NBINS     196              // ceil(100000 / 512)
#define N_NODES_B (NBINS * BIN_NODES)   // 100352 (csr/cursor allocated size)
#define BINCAP    9000             // Poisson(8192) + ~9 sigma
#define EPB       2048             // edges per phase-1 block

typedef __attribute__((ext_vector_type(8))) unsigned short us8;   // 8 bf16
typedef __attribute__((ext_vector_type(8))) short s8v;            // mfma frag_ab
typedef __attribute__((ext_vector_type(4))) float f4v;            // mfma frag_cd

__device__ __forceinline__ unsigned short f2bf(float f) {
    unsigned u = __builtin_bit_cast(unsigned, f);
    unsigned r = u + 0x7FFFu + ((u >> 16) & 1u);    // RNE
    return (unsigned short)(r >> 16);
}
__device__ __forceinline__ float bf2f(unsigned short h) {
    unsigned u = ((unsigned)h) << 16;
    return __builtin_bit_cast(float, u);
}
__device__ __forceinline__ void acc8(float* a, us8 v) {
#pragma unroll
    for (int e = 0; e < 8; e++) a[e] += bf2f(v[e]);
}

// ---------------- CSR build phase 1: bin edges by dst>>9 ----------------

__global__ __launch_bounds__(512) void bin_kernel(const int* __restrict__ src,
                                                  const int* __restrict__ dst,
                                                  int* __restrict__ bin_cursor,
                                                  int2* __restrict__ binbuf) {
    __shared__ int hist[NBINS];
    __shared__ int base[NBINS];
    const int t = threadIdx.x;
    for (int i = t; i < NBINS; i += 512) hist[i] = 0;
    __syncthreads();

    const int e0 = blockIdx.x * EPB;
    int myb[4], mys[4], myd[4], myp[4];
#pragma unroll
    for (int j = 0; j < 4; j++) {
        int e = e0 + t + j * 512;
        if (e < N_EDGES) {
            myd[j] = dst[e];
            mys[j] = src[e];
            myb[j] = myd[j] >> 9;
        } else {
            myb[j] = -1; mys[j] = 0; myd[j] = 0;
        }
    }
#pragma unroll
    for (int j = 0; j < 4; j++)
        myp[j] = (myb[j] >= 0) ? atomicAdd(&hist[myb[j]], 1) : 0;
    __syncthreads();

    for (int i = t; i < NBINS; i += 512) {
        int h = hist[i];
        base[i] = (h > 0) ? atomicAdd(&bin_cursor[i], h) : 0;
    }
    __syncthreads();

#pragma unroll
    for (int j = 0; j < 4; j++) {
        if (myb[j] >= 0) {
            int pos = base[myb[j]] + myp[j];
            if (pos < BINCAP)
                binbuf[(size_t)myb[j] * BINCAP + pos] = make_int2(mys[j], myd[j]);
        }
    }
}

// ---------------- CSR build phase 2: per-bin scatter in LDS, coalesced writeout ------

__global__ __launch_bounds__(512) void build_kernel(const int2* __restrict__ binbuf,
                                                    const int* __restrict__ bin_cursor,
                                                    int* __restrict__ cursor,
                                                    int* __restrict__ csr) {
    __shared__ int lcur[BIN_NODES];                 // 2 KB
    __shared__ int lcsr[BIN_NODES * MAXDEG];        // 128 KB
    const int b = blockIdx.x, t = threadIdx.x;
    if (t < BIN_NODES) lcur[t] = 0;
    __syncthreads();

    int cnt = bin_cursor[b];
    if (cnt > BINCAP) cnt = BINCAP;
    const int2* __restrict__ eb = binbuf + (size_t)b * BINCAP;
    for (int i = t; i < cnt; i += 512) {
        int2 e = eb[i];
        int dl = e.y - b * BIN_NODES;               // 0..511
        int p = atomicAdd(&lcur[dl], 1);
        if (p < MAXDEG) lcsr[dl * MAXDEG + p] = e.x;
    }
    __syncthreads();

    // coalesced writeout: 32768 ints = 8192 int4
    int4* __restrict__ gout = reinterpret_cast<int4*>(csr + (size_t)b * BIN_NODES * MAXDEG);
    const int4* __restrict__ lin = reinterpret_cast<const int4*>(lcsr);
    for (int i = t; i < BIN_NODES * MAXDEG / 4; i += 512) gout[i] = lin[i];
    if (t < BIN_NODES) cursor[b * BIN_NODES + t] = lcur[t];
}

// ---------------- x -> bf16 (pad rows zeroed) ----------------

__global__ void convert_x_kernel(const float* __restrict__ x, ushort* __restrict__ xh) {
    const int flat = blockIdx.x * 256 + threadIdx.x;      // one us8 per thread
    const int row = flat >> 3;                             // 8 us8 per 64-feat row
    us8 w;
    if (row < N_NODES) {
        const float* p = x + (size_t)flat * 8;
        float4 v0 = *reinterpret_cast<const float4*>(p);
        float4 v1 = *reinterpret_cast<const float4*>(p + 4);
        w[0] = f2bf(v0.x); w[1] = f2bf(v0.y); w[2] = f2bf(v0.z); w[3] = f2bf(v0.w);
        w[4] = f2bf(v1.x); w[5] = f2bf(v1.y); w[6] = f2bf(v1.z); w[7] = f2bf(v1.w);
    } else {
#pragma unroll
        for (int e = 0; e < 8; e++) w[e] = 0;
    }
    reinterpret_cast<us8*>(xh)[flat] = w;
}

// ---------------- pack weights into MFMA fragment order (bf16) ----------------
// dst[((ks*8+ct)*64+lane)*8+j] = bf16( src[(ks*32+(lane>>4)*8+j)*128 + ct*16+(lane&15)] )

__global__ void pack_weights_kernel(const float* __restrict__ s0, const float* __restrict__ s1,
                                    const float* __restrict__ s2, const float* __restrict__ s3,
                                    const float* __restrict__ s4, const float* __restrict__ s5,
                                    ushort* __restrict__ Bpk) {
    const int flat = blockIdx.x * 256 + threadIdx.x;       // < 81920
    const float* src; int base;
    if      (flat < 8192)  { src = s0; base = 0; }
    else if (flat < 16384) { src = s1; base = 8192; }
    else if (flat < 32768) { src = s2; base = 16384; }
    else if (flat < 49152) { src = s3; base = 32768; }
    else if (flat < 65536) { src = s4; base = 49152; }
    else                   { src = s5; base = 65536; }
    const int local = flat - base;
    const int j    = local & 7;
    const int lane = (local >> 3) & 63;
    const int tile = local >> 9;
    const int ks = tile >> 3, ct = tile & 7;
    const int row = ks * 32 + ((lane >> 4) << 3) + j;
    const int col = (ct << 4) + (lane & 15);
    Bpk[flat] = f2bf(src[row * 128 + col]);
}

// ------- aggregation (bf16 gather-mean, us8 lanes, 16-deep MLP for Poisson(16)) -------

template <int D>
__global__ __launch_bounds__(256, 4) void aggregate_bf(
        const ushort* __restrict__ feat, const int* __restrict__ cursor,
        const int* __restrict__ csr, ushort* __restrict__ aggout) {
    constexpr int LPN = D / 8;           // lanes per node (one us8 each)
    constexpr int NPB = 256 / LPN;
    const int tid  = threadIdx.x;
    const int lane = tid & (LPN - 1);
    const int n    = blockIdx.x * NPB + tid / LPN;
    if (n >= N_NODES) return;
    const int start = n * MAXDEG;
    int cnt = cursor[n];
    if (cnt > MAXDEG) cnt = MAXDEG;
    const us8* __restrict__ f8 = reinterpret_cast<const us8*>(feat);

    float a[8] = {0.f, 0.f, 0.f, 0.f, 0.f, 0.f, 0.f, 0.f};
    int i = 0;
    // 16-deep: covers the median Poisson(16) node in one batch; 16 gathers in flight
    for (; i + 16 <= cnt; i += 16) {
        int t[16];
#pragma unroll
        for (int u = 0; u < 16; u++) t[u] = csr[start + i + u];
        us8 v[16];
#pragma unroll
        for (int u = 0; u < 16; u++) v[u] = f8[(size_t)t[u] * LPN + lane];
#pragma unroll
        for (int u = 0; u < 16; u++) acc8(a, v[u]);
    }
    for (; i + 8 <= cnt; i += 8) {
        int t[8];
#pragma unroll
        for (int u = 0; u < 8; u++) t[u] = csr[start + i + u];
        us8 v[8];
#pragma unroll
        for (int u = 0; u < 8; u++) v[u] = f8[(size_t)t[u] * LPN + lane];
#pragma unroll
        for (int u = 0; u < 8; u++) acc8(a, v[u]);
    }
    for (; i + 4 <= cnt; i += 4) {
        int t0 = csr[start + i + 0], t1 = csr[start + i + 1];
        int t2 = csr[start + i + 2], t3 = csr[start + i + 3];
        us8 v0 = f8[(size_t)t0 * LPN + lane];
        us8 v1 = f8[(size_t)t1 * LPN + lane];
        us8 v2 = f8[(size_t)t2 * LPN + lane];
        us8 v3 = f8[(size_t)t3 * LPN + lane];
        acc8(a, v0); acc8(a, v1); acc8(a, v2); acc8(a, v3);
    }
    for (; i < cnt; i++) {
        us8 v0 = f8[(size_t)csr[start + i] * LPN + lane];
        acc8(a, v0);
    }
    const float inv = 1.f / (float)(cnt > 0 ? cnt : 1);
    us8 w;
#pragma unroll
    for (int e = 0; e < 8; e++) w[e] = f2bf(a[e] * inv);
    reinterpret_cast<us8*>(aggout)[(size_t)n * LPN + lane] = w;
}

// ---------------- MFMA GEMM: out = act(A1@B1 + A2@B2 + bias), bf16 in/out, f32 acc ----

template <int K, bool RELU>
__global__ __launch_bounds__(256, 2) void gemm_mfma(
        const ushort* __restrict__ A1, const ushort* __restrict__ A2,
        const ushort* __restrict__ B1p, const ushort* __restrict__ B2p,
        const float* __restrict__ bias, ushort* __restrict__ out) {
    constexpr int KS = K / 32;
    __shared__ ushort Bs[2 * KS * 8 * 512];     // K=128: 64KB, K=64: 32KB
    const int tid = threadIdx.x;
    {   // stage both packed B matrices linearly into LDS
        const us8* g1 = reinterpret_cast<const us8*>(B1p);
        const us8* g2 = reinterpret_cast<const us8*>(B2p);
        us8* l8 = reinterpret_cast<us8*>(Bs);
        constexpr int PH = KS * 512;
#pragma unroll
        for (int i = 0; i < 4 * KS; i++) {
            int c = i * 256 + tid;
            if (i < 2 * KS) l8[c] = g1[c];
            else            l8[c] = g2[c - PH];
        }
    }
    __syncthreads();

    const int wave = tid >> 6, lane = tid & 63;
    const int r0 = blockIdx.x * 128 + wave * 32;
    const size_t arow = (size_t)(r0 + (lane & 15));
    const int koff = (lane >> 4) << 3;

    f4v acc[2][8];
#pragma unroll
    for (int rt = 0; rt < 2; rt++)
#pragma unroll
        for (int ct = 0; ct < 8; ct++) acc[rt][ct] = (f4v){0.f, 0.f, 0.f, 0.f};

    const s8v* Bf = reinterpret_cast<const s8v*>(Bs);
#pragma unroll
    for (int ph = 0; ph < 2; ph++) {
        const ushort* __restrict__ A = ph ? A2 : A1;
#pragma unroll
        for (int ks = 0; ks < KS; ks++) {
            s8v a0 = *reinterpret_cast<const s8v*>(A + arow * K + ks * 32 + koff);
            s8v a1 = *reinterpret_cast<const s8v*>(A + (arow + 16) * K + ks * 32 + koff);
#pragma unroll
            for (int ct = 0; ct < 8; ct++) {
                s8v b = Bf[((ph * KS + ks) * 8 + ct) * 64 + lane];
                acc[0][ct] = __builtin_amdgcn_mfma_f32_16x16x32_bf16(a0, b, acc[0][ct], 0, 0, 0);
                acc[1][ct] = __builtin_amdgcn_mfma_f32_16x16x32_bf16(a1, b, acc[1][ct], 0, 0, 0);
            }
        }
    }

    // epilogue: C/D layout col=lane&15, row=(lane>>4)*4+reg  [m89]
    const int colb = lane & 15;
    const int rowb = (lane >> 4) << 2;
#pragma unroll
    for (int rt = 0; rt < 2; rt++) {
#pragma unroll
        for (int ct = 0; ct < 8; ct++) {
            const int col = ct * 16 + colb;
            const float bb = bias[col];
#pragma unroll
            for (int j = 0; j < 4; j++) {
                int row = r0 + rt * 16 + rowb + j;
                if (row < N_NODES) {
                    float v = acc[rt][ct][j] + bb;
                    if (RELU) v = fmaxf(v, 0.f);
                    out[(size_t)row * HIDDEN + col] = f2bf(v);
                }
            }
        }
    }
}

// ---------------- global mean pool (bf16 in, f32 out; one wave per graph) -------------

__global__ __launch_bounds__(256) void pool_bf(const ushort* __restrict__ h,
                                               const int* __restrict__ batch,
                                               float* __restrict__ g) {
    __shared__ int sb[5];
    const int g0 = blockIdx.x * 4;
    const int tid = threadIdx.x;
    if (tid <= 4) {
        int target = g0 + tid;
        int lo = 0, hi = N_NODES;
        while (lo < hi) {
            int mid = (lo + hi) >> 1;
            if (batch[mid] < target) lo = mid + 1; else hi = mid;
        }
        sb[tid] = lo;
    }
    __syncthreads();
    const int lg = tid >> 6;
    const int lane = tid & 63;
    const int s = sb[lg], e = sb[lg + 1];
    const int nsub = lane >> 4;
    const int cc = lane & 15;
    const us8* __restrict__ h8 = reinterpret_cast<const us8*>(h);

    float a[8] = {0.f, 0.f, 0.f, 0.f, 0.f, 0.f, 0.f, 0.f};
    int n = s + nsub;
    for (; n + 12 < e; n += 16) {
        us8 v0 = h8[(size_t)(n + 0) * 16 + cc];
        us8 v1 = h8[(size_t)(n + 4) * 16 + cc];
        us8 v2 = h8[(size_t)(n + 8) * 16 + cc];
        us8 v3 = h8[(size_t)(n + 12) * 16 + cc];
        acc8(a, v0); acc8(a, v1); acc8(a, v2); acc8(a, v3);
    }
    for (; n < e; n += 4) {
        us8 v0 = h8[(size_t)n * 16 + cc];
        acc8(a, v0);
    }
#pragma unroll
    for (int e2 = 0; e2 < 8; e2++) {
        a[e2] += __shfl_xor(a[e2], 16);
        a[e2] += __shfl_xor(a[e2], 32);
    }
    if (nsub == 0) {
        const int cnt = e - s;
        const float inv = 1.f / (float)(cnt > 0 ? cnt : 1);
        float4 w0 = make_float4(a[0] * inv, a[1] * inv, a[2] * inv, a[3] * inv);
        float4 w1 = make_float4(a[4] * inv, a[5] * inv, a[6] * inv, a[7] * inv);
        float* dst = g + (size_t)(g0 + lg) * HIDDEN + cc * 8;
        *reinterpret_cast<float4*>(dst) = w0;
        *reinterpret_cast<float4*>(dst + 4) = w1;
    }
}

// ---------------- output head: out = g @ W_out + b_out (f32 exact) ----------------

__global__ void head_kernel(const float* __restrict__ g, const float* __restrict__ W,
                            const float* __restrict__ b, float* __restrict__ out) {
    const int gid = blockIdx.x * 4 + (threadIdx.x >> 4);
    const int f = threadIdx.x & 15;
    if (gid >= N_GRAPHS) return;
    float acc = b[f];
    for (int k = 0; k < HIDDEN; k++)
        acc += g[(size_t)gid * HIDDEN + k] * W[k * N_CLASSES + f];
    out[(size_t)gid * N_CLASSES + f] = acc;
}

// ---------------- launch ----------------

extern "C" void kernel_launch(void* const* d_in, const int* in_sizes, int n_in,
                              void* d_out, int out_size, void* d_ws, size_t ws_size,
                              hipStream_t stream) {
    const float* x    = (const float*)d_in[0];
    const int* eidx   = (const int*)d_in[1];
    const int* batch  = (const int*)d_in[2];
    const float* Wl1  = (const float*)d_in[3];
    const float* bl1  = (const float*)d_in[4];
    const float* Wr1  = (const float*)d_in[5];
    const float* Wl2  = (const float*)d_in[6];
    const float* bl2  = (const float*)d_in[7];
    const float* Wr2  = (const float*)d_in[8];
    const float* Wl3  = (const float*)d_in[9];
    const float* bl3  = (const float*)d_in[10];
    const float* Wr3  = (const float*)d_in[11];
    const float* Wout = (const float*)d_in[12];
    const float* bout = (const float*)d_in[13];
    float* out = (float*)d_out;

    const int* esrc = eidx;
    const int* edst = eidx + N_EDGES;

    char* ws = (char*)d_ws;
    size_t o = 0;
    int*  bin_cursor = (int*)(ws + o);  o += 256 * 4;                        // zeroed
    int*  cursor     = (int*)(ws + o);  o += (size_t)N_NODES_B * 4;
    int*  csr        = (int*)(ws + o);  o += (size_t)N_NODES_B * MAXDEG * 4; // 25.7 MB
    int2* binbuf     = (int2*)(ws + o); o += (size_t)NBINS * BINCAP * 8;     // 14.1 MB
    o = (o + 255) & ~(size_t)255;
    ushort* xh   = (ushort*)(ws + o); o += (size_t)N_PAD * IN_FEAT * 2;
    ushort* aggb = (ushort*)(ws + o); o += (size_t)N_PAD * HIDDEN * 2;
    ushort* h1b  = (ushort*)(ws + o); o += (size_t)N_PAD * HIDDEN * 2;
    ushort* h2b  = (ushort*)(ws + o); o += (size_t)N_PAD * HIDDEN * 2;
    ushort* Bpk  = (ushort*)(ws + o); o += (size_t)81920 * 2;
    float*  g    = (float*)(ws + o);  o += (size_t)N_GRAPHS * HIDDEN * 4;

    hipMemsetAsync(bin_cursor, 0, 256 * 4, stream);

    bin_kernel<<<(N_EDGES + EPB - 1) / EPB, 512, 0, stream>>>(esrc, edst, bin_cursor, binbuf);
    build_kernel<<<NBINS, 512, 0, stream>>>(binbuf, bin_cursor, cursor, csr);

    pack_weights_kernel<<<320, 256, 0, stream>>>(Wl1, Wr1, Wl2, Wr2, Wl3, Wr3, Bpk);
    convert_x_kernel<<<(N_PAD * IN_FEAT / 8) / 256, 256, 0, stream>>>(x, xh);

    ushort* Wl1p = Bpk + 0,     *Wr1p = Bpk + 8192;
    ushort* Wl2p = Bpk + 16384, *Wr2p = Bpk + 32768;
    ushort* Wl3p = Bpk + 49152, *Wr3p = Bpk + 65536;

    const int GB = N_PAD / 128;                       // 782

    // layer 1
    aggregate_bf<IN_FEAT><<<(N_NODES + 31) / 32, 256, 0, stream>>>(xh, cursor, csr, aggb);
    gemm_mfma<IN_FEAT, true><<<GB, 256, 0, stream>>>(aggb, xh, Wl1p, Wr1p, bl1, h1b);
    // layer 2
    aggregate_bf<HIDDEN><<<(N_NODES + 15) / 16, 256, 0, stream>>>(h1b, cursor, csr, aggb);
    gemm_mfma<HIDDEN, true><<<GB, 256, 0, stream>>>(aggb, h1b, Wl2p, Wr2p, bl2, h2b);
    // layer 3 (no relu) -> write into h1b (free)
    aggregate_bf<HIDDEN><<<(N_NODES + 15) / 16, 256, 0, stream>>>(h2b, cursor, csr, aggb);
    gemm_mfma<HIDDEN, false><<<GB, 256, 0, stream>>>(aggb, h2b, Wl3p, Wr3p, bl3, h1b);

    // pool + head
    pool_bf<<<N_GRAPHS / 4, 256, 0, stream>>>(h1b, batch, g);
    head_kernel<<<N_GRAPHS / 4, 64, 0, stream>>>(g, Wout, bout, out);
}